// Round 7
// baseline (304.975 us; speedup 1.0000x reference)
//
#include <hip/hip_runtime.h>

// GraphConv GNN forward, MI355X — Round 7.
// R6 post-mortem: GEMM still latency-bound (MfmaUtil 3.6%, VGPR=72, 1.5 waves/SIMD;
// 16B B-loads serialize vs MFMA). Fix: whole weight array staged in LDS once per
// block (no K-loop barriers), M=2 row-tiles/wave (B reuse, 2 indep acc chains),
// L3 as single 782-block dispatch over 2 col-halves, launch_bounds(128,2).

#define NNODES 50000
#define NEDGES 800000
#define NGRAPH 64
#define NBUK 256                          // dst buckets
#define BSZ 196                           // nodes per bucket (196*256 >= 50000)
#define EPB (NEDGES / NBUK)               // 3125 edges per partition block
#define CVT_NB (NNODES * 128 / 4 / 256)   // 6250
#define PACK_NB (160 * 512 / 256)         // 320

typedef __attribute__((ext_vector_type(8))) __bf16 bf16x8;
typedef __attribute__((ext_vector_type(16))) float f32x16;

__device__ __forceinline__ unsigned short f2bf(float f) {
    unsigned u = __float_as_uint(f);
    u += 0x7fff + ((u >> 16) & 1);   // RNE
    return (unsigned short)(u >> 16);
}
__device__ __forceinline__ float bf2f(unsigned b) {
    return __uint_as_float(b << 16);
}

// ---------------- CSR build: counting-sort partition ----------------

__global__ void hist_kernel(const int* __restrict__ dst, int* __restrict__ cnt) {
    __shared__ int h[NBUK];
    int tid = threadIdx.x, k = blockIdx.x;
    h[tid] = 0;
    __syncthreads();
    int end = (k + 1) * EPB;
    for (int i = k * EPB + tid; i < end; i += 256)
        atomicAdd(&h[dst[i] / BSZ], 1);
    __syncthreads();
    cnt[tid * NBUK + k] = h[tid];
}

__global__ void scan1_kernel(int* __restrict__ a, int* __restrict__ bsum, int n) {
    __shared__ int buf[256];
    int tid = threadIdx.x;
    int i = blockIdx.x * 256 + tid;
    int v = (i < n) ? a[i] : 0;
    buf[tid] = v;
    __syncthreads();
    #pragma unroll
    for (int off = 1; off < 256; off <<= 1) {
        int t = (tid >= off) ? buf[tid - off] : 0;
        __syncthreads();
        buf[tid] += t;
        __syncthreads();
    }
    if (i < n) a[i] = buf[tid] - v;            // local exclusive (in-place)
    if (tid == 255) bsum[blockIdx.x] = buf[255];
}

__global__ void scan2_kernel(int* __restrict__ bsum, int nb) {
    __shared__ int buf[256];
    int tid = threadIdx.x;
    int v = (tid < nb) ? bsum[tid] : 0;
    buf[tid] = v;
    __syncthreads();
    #pragma unroll
    for (int off = 1; off < 256; off <<= 1) {
        int t = (tid >= off) ? buf[tid - off] : 0;
        __syncthreads();
        buf[tid] += t;
        __syncthreads();
    }
    if (tid < nb) bsum[tid] = buf[tid] - v;
}

__global__ void scan3_kernel(int* __restrict__ a, const int* __restrict__ bsum, int n) {
    int i = blockIdx.x * 256 + threadIdx.x;
    if (i < n) a[i] += bsum[blockIdx.x];
}

__global__ void partition_kernel(const int* __restrict__ src, const int* __restrict__ dst,
                                 const int* __restrict__ cnt,
                                 unsigned long long* __restrict__ pedge) {
    __shared__ int lbase[NBUK];
    int tid = threadIdx.x, k = blockIdx.x;
    lbase[tid] = cnt[tid * NBUK + k];
    __syncthreads();
    int end = (k + 1) * EPB;
    for (int i = k * EPB + tid; i < end; i += 256) {
        int s = src[i], d = dst[i];
        int pos = atomicAdd(&lbase[d / BSZ], 1);
        pedge[pos] = (unsigned long long)(unsigned)s | ((unsigned long long)(unsigned)d << 32);
    }
}

__global__ void build_kernel(const unsigned long long* __restrict__ pedge,
                             const int* __restrict__ cnt,
                             int* __restrict__ rp, int* __restrict__ csr) {
    __shared__ int sdeg[256], sc[256], sbase[256], sfill[256];
    int tid = threadIdx.x, b = blockIdx.x;
    int node0 = b * BSZ;
    int ncnt = NNODES - node0;
    if (ncnt > BSZ) ncnt = BSZ;
    if (ncnt < 0) ncnt = 0;
    int seg0 = cnt[b * NBUK];
    int seg1 = (b + 1 < NBUK) ? cnt[(b + 1) * NBUK] : NEDGES;
    sdeg[tid] = 0;
    sfill[tid] = 0;
    __syncthreads();
    for (int i = seg0 + tid; i < seg1; i += 256)
        atomicAdd(&sdeg[(int)(pedge[i] >> 32) - node0], 1);
    __syncthreads();
    sc[tid] = sdeg[tid];
    __syncthreads();
    #pragma unroll
    for (int off = 1; off < 256; off <<= 1) {
        int t = (tid >= off) ? sc[tid - off] : 0;
        __syncthreads();
        sc[tid] += t;
        __syncthreads();
    }
    sbase[tid] = sc[tid] - sdeg[tid];          // exclusive within bucket
    if (tid < ncnt) rp[node0 + tid] = seg0 + sbase[tid];
    if (b == NBUK - 1 && tid == 0) rp[NNODES] = NEDGES;
    __syncthreads();
    for (int i = seg0 + tid; i < seg1; i += 256) {
        unsigned long long p = pedge[i];
        int d = (int)(p >> 32) - node0;
        int pos = atomicAdd(&sfill[d], 1);
        csr[seg0 + sbase[d] + pos] = (int)(p & 0xffffffffu);
    }
}

// ---------------- merged prep: cvt + weight pack + head fold ----------------

__device__ __forceinline__ void pack32(const float* __restrict__ W, unsigned short* __restrict__ dst,
                                       int KS_tot, int ks0, int dcols, int ct0,
                                       int tl, int ksl, int lane, int j) {
    int k = ksl * 16 + ((lane >> 5) << 3) + j;
    int col = tl * 32 + (lane & 31);
    dst[(((size_t)(ct0 + tl) * KS_tot + (ks0 + ksl)) * 64 + lane) * 8 + j] = f2bf(W[k * dcols + col]);
}

__global__ void prep_kernel(const float* __restrict__ x, unsigned short* __restrict__ xbf,
                            const float* __restrict__ w1_rel, const float* __restrict__ w1_root,
                            const float* __restrict__ w2_rel, const float* __restrict__ w2_root,
                            const float* __restrict__ w3_rel, const float* __restrict__ w3_root,
                            unsigned short* __restrict__ pL1, unsigned short* __restrict__ pL2,
                            unsigned short* __restrict__ pL3,
                            const float* __restrict__ w4_rel, const float* __restrict__ w4_root,
                            const float* __restrict__ b4, const float* __restrict__ head_w,
                            float* __restrict__ wr, float* __restrict__ wt,
                            float* __restrict__ cbuf) {
    int b = blockIdx.x;
    int tid = threadIdx.x;
    if (b < CVT_NB) {                       // fp32 -> bf16 of x
        int i = b * 256 + tid;
        float4 v = ((const float4*)x)[i];
        unsigned lo = (unsigned)f2bf(v.x) | ((unsigned)f2bf(v.y) << 16);
        unsigned hi = (unsigned)f2bf(v.z) | ((unsigned)f2bf(v.w) << 16);
        ((uint2*)xbf)[i] = make_uint2(lo, hi);
    } else if (b < CVT_NB + PACK_NB) {      // weight packing (32x32x16 B-frag order)
        int idx = (b - CVT_NB) * 256 + tid;
        int g = idx >> 9;
        int t = idx & 511;
        int lane = (t >> 3) & 63, j = t & 7;
        if (g < 16)       { int gl = g;       pack32(w1_rel,  pL1, 8,  0, 64,  0, gl / 8, gl % 8, lane, j); }
        else if (g < 32)  { int gl = g - 16;  pack32(w1_root, pL1, 8,  0, 64,  2, gl / 8, gl % 8, lane, j); }
        else if (g < 48)  { int gl = g - 32;  pack32(w2_rel,  pL2, 8,  0, 128, 0, gl / 4, gl % 4, lane, j); }
        else if (g < 64)  { int gl = g - 48;  pack32(w2_root, pL2, 8,  4, 128, 0, gl / 4, gl % 4, lane, j); }
        else if (g < 112) { int gl = g - 64;  pack32(w3_rel,  pL3, 16, 0, 192, 0, gl / 8, gl % 8, lane, j); }
        else              { int gl = g - 112; pack32(w3_root, pL3, 16, 8, 192, 0, gl / 8, gl % 8, lane, j); }
    } else {                                // head folding
        if (tid < 192) {
            float ar = 0.f, at = 0.f;
            for (int j = 0; j < 64; j++) {
                float hw = head_w[j];
                ar = fmaf(w4_rel[tid * 64 + j], hw, ar);
                at = fmaf(w4_root[tid * 64 + j], hw, at);
            }
            wr[tid] = ar;
            wt[tid] = at;
        } else if (tid == 192) {
            float c = 0.f;
            for (int j = 0; j < 64; j++) c = fmaf(b4[j], head_w[j], c);
            cbuf[0] = c;
        }
    }
}

// ---------------- MFMA GEMM v3 (32x32x16, LDS-resident weights) ----------------
// Block = 2 waves (128 thr); each wave owns M=2 row-tiles (64 rows) -> 128 rows/block.
// All NT*KS B fragments staged in LDS once; K-loop barrier-free, B via ds_read.
// NHALF=2 splits output cols across blockIdx halves (one dispatch for L3).
// A frag: row = lane&31, k = (lane>>5)*8 + j. C/D: col = lane&31,
// row = (reg&3) + 8*(reg>>2) + 4*(lane>>5)   [verified m74/m101].

template<int NT, int KS, int NHALF>
__global__ __launch_bounds__(128, 2) void gemm_v3(
    const unsigned short* __restrict__ A, const unsigned short* __restrict__ Wall,
    const float* __restrict__ bias, unsigned short* __restrict__ OUT,
    int ldo, int ocol_base, int relu, int N)
{
    const int K = KS * 16;
    __shared__ unsigned short sB[NT * KS * 512];   // NT*KS fragments x 1KB

    int b = blockIdx.x;
    int halfsel = 0;
    if (NHALF == 2) {
        int nblk = gridDim.x >> 1;
        halfsel = (b >= nblk) ? 1 : 0;
        b -= halfsel * nblk;
    }
    const unsigned short* W = Wall + (size_t)halfsel * NT * KS * 512;

    int tid = threadIdx.x;
    int wave = tid >> 6, lane = tid & 63;
    int l32 = lane & 31, half = lane >> 5;

    // stage all weights (coalesced 16B/thread)
    {
        const uint4* gsrc = (const uint4*)W;
        uint4* ldst = (uint4*)sB;
        const int total = NT * KS * 64;            // uint4 count
        #pragma unroll 4
        for (int i = tid; i < total; i += 128) ldst[i] = gsrc[i];
    }

    int rbase = b * 128 + wave * 64;               // this wave: tiles rbase, rbase+32
    int ar0 = rbase + l32;        if (ar0 >= N) ar0 = N - 1;
    int ar1 = rbase + 32 + l32;   if (ar1 >= N) ar1 = N - 1;
    const unsigned short* a0p = A + (size_t)ar0 * K + half * 8;
    const unsigned short* a1p = A + (size_t)ar1 * K + half * 8;

    __syncthreads();

    f32x16 acc[2][NT];
    #pragma unroll
    for (int m = 0; m < 2; m++)
        #pragma unroll
        for (int t = 0; t < NT; t++)
            #pragma unroll
            for (int r = 0; r < 16; r++) acc[m][t][r] = 0.f;

    bf16x8 a0 = *(const bf16x8*)a0p;
    bf16x8 a1 = *(const bf16x8*)a1p;
    #pragma unroll
    for (int ks = 0; ks < KS; ks++) {
        bf16x8 a0n = a0, a1n = a1;
        if (ks + 1 < KS) {
            a0n = *(const bf16x8*)(a0p + (ks + 1) * 16);
            a1n = *(const bf16x8*)(a1p + (ks + 1) * 16);
        }
        #pragma unroll
        for (int t = 0; t < NT; t++) {
            bf16x8 bb = *(const bf16x8*)(sB + (size_t)(t * KS + ks) * 512 + lane * 8);
            acc[0][t] = __builtin_amdgcn_mfma_f32_32x32x16_bf16(a0, bb, acc[0][t], 0, 0, 0);
            acc[1][t] = __builtin_amdgcn_mfma_f32_32x32x16_bf16(a1, bb, acc[1][t], 0, 0, 0);
        }
        a0 = a0n; a1 = a1n;
    }

    #pragma unroll
    for (int m = 0; m < 2; m++) {
        #pragma unroll
        for (int t = 0; t < NT; t++) {
            int laycol = halfsel * NT * 32 + t * 32 + l32;
            float bi = bias ? bias[laycol] : 0.f;
            #pragma unroll
            for (int reg = 0; reg < 16; reg++) {
                int row = rbase + m * 32 + (reg & 3) + 8 * (reg >> 2) + 4 * half;
                if (row < N) {
                    float v = acc[m][t][reg] + bi;
                    if (relu) v = fmaxf(v, 0.f);
                    OUT[(size_t)row * ldo + ocol_base + laycol] = f2bf(v);
                }
            }
        }
    }
}

// ---------------- bf16 neighbor-sum via CSR gather ----------------

__device__ __forceinline__ void acc8(float* a, uint4 u) {
    a[0] += bf2f(u.x & 0xffffu); a[1] += bf2f(u.x >> 16);
    a[2] += bf2f(u.y & 0xffffu); a[3] += bf2f(u.y >> 16);
    a[4] += bf2f(u.z & 0xffffu); a[5] += bf2f(u.z >> 16);
    a[6] += bf2f(u.w & 0xffffu); a[7] += bf2f(u.w >> 16);
}

template<int LPF>
__global__ void agg_kernel_v2(const unsigned short* __restrict__ X, int ldx,
                              const int* __restrict__ rp, const int* __restrict__ csr,
                              const unsigned short* __restrict__ root, int ldr,
                              const float* __restrict__ bias, int relu,
                              unsigned short* __restrict__ OUT, int ldo, int N) {
    int t = blockIdx.x * blockDim.x + threadIdx.x;
    int node = t / (2 * LPF);
    int r = t % (2 * LPF);
    int sub = r / LPF;
    int sl = r % LPF;
    if (node >= N) return;
    float a[8] = {0.f, 0.f, 0.f, 0.f, 0.f, 0.f, 0.f, 0.f};
    int e0 = rp[node], e1 = rp[node + 1];
    const unsigned short* xb = X + 8 * sl;
    int e = e0 + sub;
    for (; e + 2 < e1; e += 4) {          // this sub: edges e, e+2
        int s0 = csr[e], s1 = csr[e + 2];
        uint4 u0 = *(const uint4*)(xb + (size_t)s0 * ldx);
        uint4 u1 = *(const uint4*)(xb + (size_t)s1 * ldx);
        acc8(a, u0);
        acc8(a, u1);
    }
    if (e < e1) {
        uint4 u = *(const uint4*)(xb + (size_t)csr[e] * ldx);
        acc8(a, u);
    }
    #pragma unroll
    for (int i = 0; i < 8; i++) a[i] += __shfl_xor(a[i], LPF, 64);
    if (sub == 0) {
        if (root) {
            uint4 u = *(const uint4*)(root + (size_t)node * ldr + 8 * sl);
            acc8(a, u);
        }
        if (bias) {
            float4 b0 = *(const float4*)(bias + 8 * sl);
            float4 b1 = *(const float4*)(bias + 8 * sl + 4);
            a[0] += b0.x; a[1] += b0.y; a[2] += b0.z; a[3] += b0.w;
            a[4] += b1.x; a[5] += b1.y; a[6] += b1.z; a[7] += b1.w;
        }
        if (relu) {
            #pragma unroll
            for (int i = 0; i < 8; i++) a[i] = fmaxf(a[i], 0.f);
        }
        uint4 o;
        o.x = (unsigned)f2bf(a[0]) | ((unsigned)f2bf(a[1]) << 16);
        o.y = (unsigned)f2bf(a[2]) | ((unsigned)f2bf(a[3]) << 16);
        o.z = (unsigned)f2bf(a[4]) | ((unsigned)f2bf(a[5]) << 16);
        o.w = (unsigned)f2bf(a[6]) | ((unsigned)f2bf(a[7]) << 16);
        *(uint4*)(OUT + (size_t)node * ldo + 8 * sl) = o;
    }
}

// ---------------- layer-4 tail ----------------

__global__ void st_kernel(const unsigned short* __restrict__ h3, const float* __restrict__ wr,
                          const float* __restrict__ wt, float* __restrict__ s,
                          float* __restrict__ t, int N) {
    int lane = threadIdx.x & 63;
    int node = (blockIdx.x * blockDim.x + threadIdx.x) >> 6;
    if (node >= N) return;
    float as = 0.f, at = 0.f;
    if (lane < 48) {
        uint2 u = *(const uint2*)(h3 + (size_t)node * 192 + 4 * lane);
        float x0 = bf2f(u.x & 0xffffu), x1 = bf2f(u.x >> 16);
        float x2 = bf2f(u.y & 0xffffu), x3 = bf2f(u.y >> 16);
        float4 r4 = *(const float4*)(wr + 4 * lane);
        float4 t4 = *(const float4*)(wt + 4 * lane);
        as = x0 * r4.x + x1 * r4.y + x2 * r4.z + x3 * r4.w;
        at = x0 * t4.x + x1 * t4.y + x2 * t4.z + x3 * t4.w;
    }
    #pragma unroll
    for (int off = 32; off > 0; off >>= 1) {
        as += __shfl_down(as, off, 64);
        at += __shfl_down(at, off, 64);
    }
    if (lane == 0) { s[node] = as; t[node] = at; }
}

__global__ void aggpool_kernel(const float* __restrict__ s, const float* __restrict__ t,
                               const int* __restrict__ rp, const int* __restrict__ csr,
                               const int* __restrict__ batch, float* __restrict__ gsum,
                               int* __restrict__ cnt, int N) {
    __shared__ float ls[NGRAPH];
    __shared__ int lc[NGRAPH];
    int tid = threadIdx.x;
    if (tid < NGRAPH) { ls[tid] = 0.f; lc[tid] = 0; }
    __syncthreads();
    int n = blockIdx.x * blockDim.x + tid;
    if (n < N) {
        float a = 0.f;
        int e = rp[n], e1 = rp[n + 1];
        for (; e + 3 < e1; e += 4) {
            int s0 = csr[e], s1 = csr[e + 1], s2 = csr[e + 2], s3 = csr[e + 3];
            a += s[s0] + s[s1] + s[s2] + s[s3];
        }
        for (; e < e1; e++) a += s[csr[e]];
        int g = batch[n];
        atomicAdd(&ls[g], a + t[n]);
        atomicAdd(&lc[g], 1);
    }
    __syncthreads();
    if (tid < NGRAPH && lc[tid] > 0) {
        atomicAdd(&gsum[tid], ls[tid]);
        atomicAdd(&cnt[tid], lc[tid]);
    }
}

__global__ void final_kernel(const float* __restrict__ gsum, const int* __restrict__ cnt,
                             const float* __restrict__ cbuf, const float* __restrict__ head_b,
                             float* __restrict__ out) {
    int g = threadIdx.x;
    if (g < NGRAPH) {
        float c = (float)(cnt[g] > 0 ? cnt[g] : 1);
        out[g] = gsum[g] / c + cbuf[0] + head_b[0];
    }
}

// ---------------- launch ----------------

extern "C" void kernel_launch(void* const* d_in, const int* in_sizes, int n_in,
                              void* d_out, int out_size, void* d_ws, size_t ws_size,
                              hipStream_t stream) {
    const float* x       = (const float*)d_in[0];
    const int*   edge    = (const int*)d_in[1];
    const int*   batch   = (const int*)d_in[2];
    const float* w1_rel  = (const float*)d_in[3];
    const float* w1_root = (const float*)d_in[4];
    const float* b1      = (const float*)d_in[5];
    const float* w2_rel  = (const float*)d_in[6];
    const float* w2_root = (const float*)d_in[7];
    const float* b2      = (const float*)d_in[8];
    const float* w3_rel  = (const float*)d_in[9];
    const float* w3_root = (const float*)d_in[10];
    const float* b3      = (const float*)d_in[11];
    const float* w4_rel  = (const float*)d_in[12];
    const float* w4_root = (const float*)d_in[13];
    const float* b4      = (const float*)d_in[14];
    const float* head_w  = (const float*)d_in[15];
    const float* head_b  = (const float*)d_in[16];
    float* out = (float*)d_out;

    const int N = NNODES, E = NEDGES;
    const int* src = edge;
    const int* dst = edge + E;

    char* ws = (char*)d_ws;
    size_t off = 0;
    auto alloc = [&](size_t bytes) -> char* {
        char* p = ws + off;
        off = (off + bytes + 255) & ~(size_t)255;
        return p;
    };
    // zeroed region first (single small memset): gsum, cnt
    float* gsum  = (float*)alloc(NGRAPH * 4);
    int*   cnt   = (int*)alloc(NGRAPH * 4);
    size_t zero_bytes = off;
    int*   bcnt  = (int*)alloc((size_t)NBUK * NBUK * 4);   // bucket x block counts
    int*   bsum  = (int*)alloc(256 * 4);
    int*   rp    = (int*)alloc((size_t)(N + 1) * 4);
    int*   csr   = (int*)alloc((size_t)E * 4);
    unsigned long long* pedge = (unsigned long long*)alloc((size_t)E * 8);
    unsigned short* xbf    = (unsigned short*)alloc((size_t)N * 128 * 2);
    unsigned short* z1     = (unsigned short*)alloc((size_t)N * 128 * 2);  // [x@w1_rel | x@w1_root]
    unsigned short* combo2 = (unsigned short*)alloc((size_t)N * 128 * 2);  // [agg2 | h1]
    unsigned short* combo3 = (unsigned short*)alloc((size_t)N * 256 * 2);  // [agg3 | h2]
    unsigned short* h3     = (unsigned short*)alloc((size_t)N * 192 * 2);
    unsigned short* pL1    = (unsigned short*)alloc(4 * 8 * 512 * 2);
    unsigned short* pL2    = (unsigned short*)alloc(4 * 8 * 512 * 2);
    unsigned short* pL3    = (unsigned short*)alloc(6 * 16 * 512 * 2);
    float* sbuf  = (float*)alloc((size_t)N * 4);
    float* tbuf  = (float*)alloc((size_t)N * 4);
    float* wr    = (float*)alloc(192 * 4);
    float* wt    = (float*)alloc(192 * 4);
    float* cbuf  = (float*)alloc(4);
    (void)ws_size;

    hipMemsetAsync(gsum, 0, zero_bytes, stream);

    const int TB = 256;

    // CSR build via counting-sort partition
    hist_kernel<<<NBUK, 256, 0, stream>>>(dst, bcnt);
    scan1_kernel<<<NBUK, 256, 0, stream>>>(bcnt, bsum, NBUK * NBUK);
    scan2_kernel<<<1, 256, 0, stream>>>(bsum, NBUK);
    scan3_kernel<<<NBUK, 256, 0, stream>>>(bcnt, bsum, NBUK * NBUK);
    partition_kernel<<<NBUK, 256, 0, stream>>>(src, dst, bcnt, pedge);
    build_kernel<<<NBUK, 256, 0, stream>>>(pedge, bcnt, rp, csr);

    // prep (cvt + pack + head fold in one launch)
    prep_kernel<<<CVT_NB + PACK_NB + 1, 256, 0, stream>>>(
        x, xbf, w1_rel, w1_root, w2_rel, w2_root, w3_rel, w3_root,
        pL1, pL2, pL3, w4_rel, w4_root, b4, head_w, wr, wt, cbuf);

    int ggrid = (N + 127) / 128;   // 391

    // L1: z1 = xbf @ [w1_rel | w1_root]
    gemm_v3<4, 8, 1><<<ggrid, 128, 0, stream>>>(xbf, pL1, nullptr, z1, 128, 0, 0, N);
    // h1 = relu( nbrsum(z1[:,:64]) + z1[:,64:] + b1 ) -> combo2[:,64:]
    agg_kernel_v2<8><<<(N * 16 + TB - 1) / TB, TB, 0, stream>>>(z1, 128, rp, csr,
                                                                z1 + 64, 128, b1, 1, combo2 + 64, 128, N);
    // agg2 = nbrsum(h1) -> combo2[:,:64]
    agg_kernel_v2<8><<<(N * 16 + TB - 1) / TB, TB, 0, stream>>>(combo2 + 64, 128, rp, csr,
                                                                nullptr, 0, nullptr, 0, combo2, 128, N);
    // L2: h2 = relu(combo2 @ [w2_rel; w2_root] + b2) -> combo3[:,128:]
    gemm_v3<4, 8, 1><<<ggrid, 128, 0, stream>>>(combo2, pL2, b2, combo3, 256, 128, 1, N);
    // agg3 = nbrsum(h2) -> combo3[:,:128]
    agg_kernel_v2<16><<<(N * 32 + TB - 1) / TB, TB, 0, stream>>>(combo3 + 128, 256, rp, csr,
                                                                 nullptr, 0, nullptr, 0, combo3, 256, N);
    // L3: h3 = relu(combo3 @ [w3_rel; w3_root] + b3)  — one dispatch, 2 col-halves
    gemm_v3<3, 16, 2><<<2 * ggrid, 128, 0, stream>>>(combo3, pL3, b3, h3, 192, 0, 1, N);

    // L4 folded with head
    st_kernel<<<(N * 64 + TB - 1) / TB, TB, 0, stream>>>(h3, wr, wt, sbuf, tbuf, N);
    aggpool_kernel<<<(N + TB - 1) / TB, TB, 0, stream>>>(sbuf, tbuf, rp, csr, batch, gsum, cnt, N);
    final_kernel<<<1, 64, 0, stream>>>(gsum, cnt, cbuf, head_b, out);
}

// Round 8
// 284.559 us; speedup vs baseline: 1.0717x; 1.0717x over previous
//
#include <hip/hip_runtime.h>

// GraphConv GNN forward, MI355X — Round 8.
// R7 post-mortem: LDS-staged GEMM regressed (occupancy 2.6 waves/CU, 1-ahead A
// prefetch -> ~16 dependent HBM latencies/wave, 1TB/s). v4: no LDS; one wave =
// 32 rows x 32 cols; K in batches of 8: 16 independent 16B loads (A+B) then 8
// register MFMAs. launch_bounds(256,4) -> ~4 waves/SIMD, HBM-throughput-bound.

#define NNODES 50000
#define NEDGES 800000
#define NGRAPH 64
#define NBUK 256                          // dst buckets
#define BSZ 196                           // nodes per bucket (196*256 >= 50000)
#define EPB (NEDGES / NBUK)               // 3125 edges per partition block
#define CVT_NB (NNODES * 128 / 4 / 256)   // 6250
#define PACK_NB (160 * 512 / 256)         // 320

typedef __attribute__((ext_vector_type(8))) __bf16 bf16x8;
typedef __attribute__((ext_vector_type(16))) float f32x16;

__device__ __forceinline__ unsigned short f2bf(float f) {
    unsigned u = __float_as_uint(f);
    u += 0x7fff + ((u >> 16) & 1);   // RNE
    return (unsigned short)(u >> 16);
}
__device__ __forceinline__ float bf2f(unsigned b) {
    return __uint_as_float(b << 16);
}

// ---------------- CSR build: counting-sort partition ----------------

__global__ void hist_kernel(const int* __restrict__ dst, int* __restrict__ cnt) {
    __shared__ int h[NBUK];
    int tid = threadIdx.x, k = blockIdx.x;
    h[tid] = 0;
    __syncthreads();
    int end = (k + 1) * EPB;
    for (int i = k * EPB + tid; i < end; i += 256)
        atomicAdd(&h[dst[i] / BSZ], 1);
    __syncthreads();
    cnt[tid * NBUK + k] = h[tid];
}

__global__ void scan1_kernel(int* __restrict__ a, int* __restrict__ bsum, int n) {
    __shared__ int buf[256];
    int tid = threadIdx.x;
    int i = blockIdx.x * 256 + tid;
    int v = (i < n) ? a[i] : 0;
    buf[tid] = v;
    __syncthreads();
    #pragma unroll
    for (int off = 1; off < 256; off <<= 1) {
        int t = (tid >= off) ? buf[tid - off] : 0;
        __syncthreads();
        buf[tid] += t;
        __syncthreads();
    }
    if (i < n) a[i] = buf[tid] - v;            // local exclusive (in-place)
    if (tid == 255) bsum[blockIdx.x] = buf[255];
}

__global__ void scan2_kernel(int* __restrict__ bsum, int nb) {
    __shared__ int buf[256];
    int tid = threadIdx.x;
    int v = (tid < nb) ? bsum[tid] : 0;
    buf[tid] = v;
    __syncthreads();
    #pragma unroll
    for (int off = 1; off < 256; off <<= 1) {
        int t = (tid >= off) ? buf[tid - off] : 0;
        __syncthreads();
        buf[tid] += t;
        __syncthreads();
    }
    if (tid < nb) bsum[tid] = buf[tid] - v;
}

__global__ void scan3_kernel(int* __restrict__ a, const int* __restrict__ bsum, int n) {
    int i = blockIdx.x * 256 + threadIdx.x;
    if (i < n) a[i] += bsum[blockIdx.x];
}

__global__ void partition_kernel(const int* __restrict__ src, const int* __restrict__ dst,
                                 const int* __restrict__ cnt,
                                 unsigned long long* __restrict__ pedge) {
    __shared__ int lbase[NBUK];
    int tid = threadIdx.x, k = blockIdx.x;
    lbase[tid] = cnt[tid * NBUK + k];
    __syncthreads();
    int end = (k + 1) * EPB;
    for (int i = k * EPB + tid; i < end; i += 256) {
        int s = src[i], d = dst[i];
        int pos = atomicAdd(&lbase[d / BSZ], 1);
        pedge[pos] = (unsigned long long)(unsigned)s | ((unsigned long long)(unsigned)d << 32);
    }
}

__global__ void build_kernel(const unsigned long long* __restrict__ pedge,
                             const int* __restrict__ cnt,
                             int* __restrict__ rp, int* __restrict__ csr) {
    __shared__ int sdeg[256], sc[256], sbase[256], sfill[256];
    int tid = threadIdx.x, b = blockIdx.x;
    int node0 = b * BSZ;
    int ncnt = NNODES - node0;
    if (ncnt > BSZ) ncnt = BSZ;
    if (ncnt < 0) ncnt = 0;
    int seg0 = cnt[b * NBUK];
    int seg1 = (b + 1 < NBUK) ? cnt[(b + 1) * NBUK] : NEDGES;
    sdeg[tid] = 0;
    sfill[tid] = 0;
    __syncthreads();
    for (int i = seg0 + tid; i < seg1; i += 256)
        atomicAdd(&sdeg[(int)(pedge[i] >> 32) - node0], 1);
    __syncthreads();
    sc[tid] = sdeg[tid];
    __syncthreads();
    #pragma unroll
    for (int off = 1; off < 256; off <<= 1) {
        int t = (tid >= off) ? sc[tid - off] : 0;
        __syncthreads();
        sc[tid] += t;
        __syncthreads();
    }
    sbase[tid] = sc[tid] - sdeg[tid];          // exclusive within bucket
    if (tid < ncnt) rp[node0 + tid] = seg0 + sbase[tid];
    if (b == NBUK - 1 && tid == 0) rp[NNODES] = NEDGES;
    __syncthreads();
    for (int i = seg0 + tid; i < seg1; i += 256) {
        unsigned long long p = pedge[i];
        int d = (int)(p >> 32) - node0;
        int pos = atomicAdd(&sfill[d], 1);
        csr[seg0 + sbase[d] + pos] = (int)(p & 0xffffffffu);
    }
}

// ---------------- merged prep: cvt + weight pack + head fold ----------------

__device__ __forceinline__ void pack32(const float* __restrict__ W, unsigned short* __restrict__ dst,
                                       int KS_tot, int ks0, int dcols, int ct0,
                                       int tl, int ksl, int lane, int j) {
    int k = ksl * 16 + ((lane >> 5) << 3) + j;
    int col = tl * 32 + (lane & 31);
    dst[(((size_t)(ct0 + tl) * KS_tot + (ks0 + ksl)) * 64 + lane) * 8 + j] = f2bf(W[k * dcols + col]);
}

__global__ void prep_kernel(const float* __restrict__ x, unsigned short* __restrict__ xbf,
                            const float* __restrict__ w1_rel, const float* __restrict__ w1_root,
                            const float* __restrict__ w2_rel, const float* __restrict__ w2_root,
                            const float* __restrict__ w3_rel, const float* __restrict__ w3_root,
                            unsigned short* __restrict__ pL1, unsigned short* __restrict__ pL2,
                            unsigned short* __restrict__ pL3,
                            const float* __restrict__ w4_rel, const float* __restrict__ w4_root,
                            const float* __restrict__ b4, const float* __restrict__ head_w,
                            float* __restrict__ wr, float* __restrict__ wt,
                            float* __restrict__ cbuf) {
    int b = blockIdx.x;
    int tid = threadIdx.x;
    if (b < CVT_NB) {                       // fp32 -> bf16 of x
        int i = b * 256 + tid;
        float4 v = ((const float4*)x)[i];
        unsigned lo = (unsigned)f2bf(v.x) | ((unsigned)f2bf(v.y) << 16);
        unsigned hi = (unsigned)f2bf(v.z) | ((unsigned)f2bf(v.w) << 16);
        ((uint2*)xbf)[i] = make_uint2(lo, hi);
    } else if (b < CVT_NB + PACK_NB) {      // weight packing (32x32x16 B-frag order)
        int idx = (b - CVT_NB) * 256 + tid;
        int g = idx >> 9;
        int t = idx & 511;
        int lane = (t >> 3) & 63, j = t & 7;
        if (g < 16)       { int gl = g;       pack32(w1_rel,  pL1, 8,  0, 64,  0, gl / 8, gl % 8, lane, j); }
        else if (g < 32)  { int gl = g - 16;  pack32(w1_root, pL1, 8,  0, 64,  2, gl / 8, gl % 8, lane, j); }
        else if (g < 48)  { int gl = g - 32;  pack32(w2_rel,  pL2, 8,  0, 128, 0, gl / 4, gl % 4, lane, j); }
        else if (g < 64)  { int gl = g - 48;  pack32(w2_root, pL2, 8,  4, 128, 0, gl / 4, gl % 4, lane, j); }
        else if (g < 112) { int gl = g - 64;  pack32(w3_rel,  pL3, 16, 0, 192, 0, gl / 8, gl % 8, lane, j); }
        else              { int gl = g - 112; pack32(w3_root, pL3, 16, 8, 192, 0, gl / 8, gl % 8, lane, j); }
    } else {                                // head folding
        if (tid < 192) {
            float ar = 0.f, at = 0.f;
            for (int j = 0; j < 64; j++) {
                float hw = head_w[j];
                ar = fmaf(w4_rel[tid * 64 + j], hw, ar);
                at = fmaf(w4_root[tid * 64 + j], hw, at);
            }
            wr[tid] = ar;
            wt[tid] = at;
        } else if (tid == 192) {
            float c = 0.f;
            for (int j = 0; j < 64; j++) c = fmaf(b4[j], head_w[j], c);
            cbuf[0] = c;
        }
    }
}

// ---------------- MFMA GEMM v4 (32x32x16, all-register, batched loads) -------
// One wave = 32 rows x 32 cols. Col-group = blockIdx % NC (A-sharing blocks
// adjacent). K in batches of 8 fragments: 8 A + 8 B loads issued together
// (16 independent 16B loads in flight), then 8 MFMAs from registers.
// A frag: row = lane&31, k = (lane>>5)*8 + j. C/D: col = lane&31,
// row = (reg&3) + 8*(reg>>2) + 4*(lane>>5)   [verified m74/m101].

template<int KS, int NC>
__global__ __launch_bounds__(256, 4) void gemm_v4(
    const unsigned short* __restrict__ A, const unsigned short* __restrict__ W,
    const float* __restrict__ bias, unsigned short* __restrict__ OUT,
    int ldo, int ocol0, int relu, int N)
{
    const int K = KS * 16;
    int b = blockIdx.x;
    int cg = b % NC, rowb = b / NC;
    int tid = threadIdx.x;
    int wave = tid >> 6, lane = tid & 63;
    int l32 = lane & 31, half = lane >> 5;
    int rbase = rowb * 128 + wave * 32;
    if (rbase >= N) return;

    int arow = rbase + l32;
    if (arow >= N) arow = N - 1;   // clamp; garbage rows never stored
    const unsigned short* ap = A + (size_t)arow * K + half * 8;
    const unsigned short* wp = W + (size_t)cg * KS * 512 + lane * 8;

    f32x16 acc;
    #pragma unroll
    for (int r = 0; r < 16; r++) acc[r] = 0.f;

    #pragma unroll 1
    for (int kb = 0; kb < KS; kb += 8) {
        bf16x8 areg[8], breg[8];
        #pragma unroll
        for (int j = 0; j < 8; j++) {
            areg[j] = *(const bf16x8*)(ap + (kb + j) * 16);
            breg[j] = *(const bf16x8*)(wp + (size_t)(kb + j) * 512);
        }
        #pragma unroll
        for (int j = 0; j < 8; j++)
            acc = __builtin_amdgcn_mfma_f32_32x32x16_bf16(areg[j], breg[j], acc, 0, 0, 0);
    }

    int col = cg * 32 + l32;
    float bi = bias ? bias[col] : 0.f;
    #pragma unroll
    for (int reg = 0; reg < 16; reg++) {
        int row = rbase + (reg & 3) + 8 * (reg >> 2) + 4 * half;
        if (row < N) {
            float v = acc[reg] + bi;
            if (relu) v = fmaxf(v, 0.f);
            OUT[(size_t)row * ldo + ocol0 + col] = f2bf(v);
        }
    }
}

// ---------------- bf16 neighbor-sum via CSR gather ----------------

__device__ __forceinline__ void acc8(float* a, uint4 u) {
    a[0] += bf2f(u.x & 0xffffu); a[1] += bf2f(u.x >> 16);
    a[2] += bf2f(u.y & 0xffffu); a[3] += bf2f(u.y >> 16);
    a[4] += bf2f(u.z & 0xffffu); a[5] += bf2f(u.z >> 16);
    a[6] += bf2f(u.w & 0xffffu); a[7] += bf2f(u.w >> 16);
}

template<int LPF>
__global__ void agg_kernel_v2(const unsigned short* __restrict__ X, int ldx,
                              const int* __restrict__ rp, const int* __restrict__ csr,
                              const unsigned short* __restrict__ root, int ldr,
                              const float* __restrict__ bias, int relu,
                              unsigned short* __restrict__ OUT, int ldo, int N) {
    int t = blockIdx.x * blockDim.x + threadIdx.x;
    int node = t / (2 * LPF);
    int r = t % (2 * LPF);
    int sub = r / LPF;
    int sl = r % LPF;
    if (node >= N) return;
    float a[8] = {0.f, 0.f, 0.f, 0.f, 0.f, 0.f, 0.f, 0.f};
    int e0 = rp[node], e1 = rp[node + 1];
    const unsigned short* xb = X + 8 * sl;
    int e = e0 + sub;
    for (; e + 2 < e1; e += 4) {          // this sub: edges e, e+2
        int s0 = csr[e], s1 = csr[e + 2];
        uint4 u0 = *(const uint4*)(xb + (size_t)s0 * ldx);
        uint4 u1 = *(const uint4*)(xb + (size_t)s1 * ldx);
        acc8(a, u0);
        acc8(a, u1);
    }
    if (e < e1) {
        uint4 u = *(const uint4*)(xb + (size_t)csr[e] * ldx);
        acc8(a, u);
    }
    #pragma unroll
    for (int i = 0; i < 8; i++) a[i] += __shfl_xor(a[i], LPF, 64);
    if (sub == 0) {
        if (root) {
            uint4 u = *(const uint4*)(root + (size_t)node * ldr + 8 * sl);
            acc8(a, u);
        }
        if (bias) {
            float4 b0 = *(const float4*)(bias + 8 * sl);
            float4 b1 = *(const float4*)(bias + 8 * sl + 4);
            a[0] += b0.x; a[1] += b0.y; a[2] += b0.z; a[3] += b0.w;
            a[4] += b1.x; a[5] += b1.y; a[6] += b1.z; a[7] += b1.w;
        }
        if (relu) {
            #pragma unroll
            for (int i = 0; i < 8; i++) a[i] = fmaxf(a[i], 0.f);
        }
        uint4 o;
        o.x = (unsigned)f2bf(a[0]) | ((unsigned)f2bf(a[1]) << 16);
        o.y = (unsigned)f2bf(a[2]) | ((unsigned)f2bf(a[3]) << 16);
        o.z = (unsigned)f2bf(a[4]) | ((unsigned)f2bf(a[5]) << 16);
        o.w = (unsigned)f2bf(a[6]) | ((unsigned)f2bf(a[7]) << 16);
        *(uint4*)(OUT + (size_t)node * ldo + 8 * sl) = o;
    }
}

// ---------------- layer-4 tail ----------------

__global__ void st_kernel(const unsigned short* __restrict__ h3, const float* __restrict__ wr,
                          const float* __restrict__ wt, float* __restrict__ s,
                          float* __restrict__ t, int N) {
    int lane = threadIdx.x & 63;
    int node = (blockIdx.x * blockDim.x + threadIdx.x) >> 6;
    if (node >= N) return;
    float as = 0.f, at = 0.f;
    if (lane < 48) {
        uint2 u = *(const uint2*)(h3 + (size_t)node * 192 + 4 * lane);
        float x0 = bf2f(u.x & 0xffffu), x1 = bf2f(u.x >> 16);
        float x2 = bf2f(u.y & 0xffffu), x3 = bf2f(u.y >> 16);
        float4 r4 = *(const float4*)(wr + 4 * lane);
        float4 t4 = *(const float4*)(wt + 4 * lane);
        as = x0 * r4.x + x1 * r4.y + x2 * r4.z + x3 * r4.w;
        at = x0 * t4.x + x1 * t4.y + x2 * t4.z + x3 * t4.w;
    }
    #pragma unroll
    for (int off = 32; off > 0; off >>= 1) {
        as += __shfl_down(as, off, 64);
        at += __shfl_down(at, off, 64);
    }
    if (lane == 0) { s[node] = as; t[node] = at; }
}

__global__ void aggpool_kernel(const float* __restrict__ s, const float* __restrict__ t,
                               const int* __restrict__ rp, const int* __restrict__ csr,
                               const int* __restrict__ batch, float* __restrict__ gsum,
                               int* __restrict__ cnt, int N) {
    __shared__ float ls[NGRAPH];
    __shared__ int lc[NGRAPH];
    int tid = threadIdx.x;
    if (tid < NGRAPH) { ls[tid] = 0.f; lc[tid] = 0; }
    __syncthreads();
    int n = blockIdx.x * blockDim.x + tid;
    if (n < N) {
        float a = 0.f;
        int e = rp[n], e1 = rp[n + 1];
        for (; e + 3 < e1; e += 4) {
            int s0 = csr[e], s1 = csr[e + 1], s2 = csr[e + 2], s3 = csr[e + 3];
            a += s[s0] + s[s1] + s[s2] + s[s3];
        }
        for (; e < e1; e++) a += s[csr[e]];
        int g = batch[n];
        atomicAdd(&ls[g], a + t[n]);
        atomicAdd(&lc[g], 1);
    }
    __syncthreads();
    if (tid < NGRAPH && lc[tid] > 0) {
        atomicAdd(&gsum[tid], ls[tid]);
        atomicAdd(&cnt[tid], lc[tid]);
    }
}

__global__ void final_kernel(const float* __restrict__ gsum, const int* __restrict__ cnt,
                             const float* __restrict__ cbuf, const float* __restrict__ head_b,
                             float* __restrict__ out) {
    int g = threadIdx.x;
    if (g < NGRAPH) {
        float c = (float)(cnt[g] > 0 ? cnt[g] : 1);
        out[g] = gsum[g] / c + cbuf[0] + head_b[0];
    }
}

// ---------------- launch ----------------

extern "C" void kernel_launch(void* const* d_in, const int* in_sizes, int n_in,
                              void* d_out, int out_size, void* d_ws, size_t ws_size,
                              hipStream_t stream) {
    const float* x       = (const float*)d_in[0];
    const int*   edge    = (const int*)d_in[1];
    const int*   batch   = (const int*)d_in[2];
    const float* w1_rel  = (const float*)d_in[3];
    const float* w1_root = (const float*)d_in[4];
    const float* b1      = (const float*)d_in[5];
    const float* w2_rel  = (const float*)d_in[6];
    const float* w2_root = (const float*)d_in[7];
    const float* b2      = (const float*)d_in[8];
    const float* w3_rel  = (const float*)d_in[9];
    const float* w3_root = (const float*)d_in[10];
    const float* b3      = (const float*)d_in[11];
    const float* w4_rel  = (const float*)d_in[12];
    const float* w4_root = (const float*)d_in[13];
    const float* b4      = (const float*)d_in[14];
    const float* head_w  = (const float*)d_in[15];
    const float* head_b  = (const float*)d_in[16];
    float* out = (float*)d_out;

    const int N = NNODES, E = NEDGES;
    const int* src = edge;
    const int* dst = edge + E;

    char* ws = (char*)d_ws;
    size_t off = 0;
    auto alloc = [&](size_t bytes) -> char* {
        char* p = ws + off;
        off = (off + bytes + 255) & ~(size_t)255;
        return p;
    };
    // zeroed region first (single small memset): gsum, cnt
    float* gsum  = (float*)alloc(NGRAPH * 4);
    int*   cnt   = (int*)alloc(NGRAPH * 4);
    size_t zero_bytes = off;
    int*   bcnt  = (int*)alloc((size_t)NBUK * NBUK * 4);   // bucket x block counts
    int*   bsum  = (int*)alloc(256 * 4);
    int*   rp    = (int*)alloc((size_t)(N + 1) * 4);
    int*   csr   = (int*)alloc((size_t)E * 4);
    unsigned long long* pedge = (unsigned long long*)alloc((size_t)E * 8);
    unsigned short* xbf    = (unsigned short*)alloc((size_t)N * 128 * 2);
    unsigned short* z1     = (unsigned short*)alloc((size_t)N * 128 * 2);  // [x@w1_rel | x@w1_root]
    unsigned short* combo2 = (unsigned short*)alloc((size_t)N * 128 * 2);  // [agg2 | h1]
    unsigned short* combo3 = (unsigned short*)alloc((size_t)N * 256 * 2);  // [agg3 | h2]
    unsigned short* h3     = (unsigned short*)alloc((size_t)N * 192 * 2);
    unsigned short* pL1    = (unsigned short*)alloc(4 * 8 * 512 * 2);
    unsigned short* pL2    = (unsigned short*)alloc(4 * 8 * 512 * 2);
    unsigned short* pL3    = (unsigned short*)alloc(6 * 16 * 512 * 2);
    float* sbuf  = (float*)alloc((size_t)N * 4);
    float* tbuf  = (float*)alloc((size_t)N * 4);
    float* wr    = (float*)alloc(192 * 4);
    float* wt    = (float*)alloc(192 * 4);
    float* cbuf  = (float*)alloc(4);
    (void)ws_size;

    hipMemsetAsync(gsum, 0, zero_bytes, stream);

    const int TB = 256;

    // CSR build via counting-sort partition
    hist_kernel<<<NBUK, 256, 0, stream>>>(dst, bcnt);
    scan1_kernel<<<NBUK, 256, 0, stream>>>(bcnt, bsum, NBUK * NBUK);
    scan2_kernel<<<1, 256, 0, stream>>>(bsum, NBUK);
    scan3_kernel<<<NBUK, 256, 0, stream>>>(bcnt, bsum, NBUK * NBUK);
    partition_kernel<<<NBUK, 256, 0, stream>>>(src, dst, bcnt, pedge);
    build_kernel<<<NBUK, 256, 0, stream>>>(pedge, bcnt, rp, csr);

    // prep (cvt + pack + head fold in one launch)
    prep_kernel<<<CVT_NB + PACK_NB + 1, 256, 0, stream>>>(
        x, xbf, w1_rel, w1_root, w2_rel, w2_root, w3_rel, w3_root,
        pL1, pL2, pL3, w4_rel, w4_root, b4, head_w, wr, wt, cbuf);

    int rgrid = (N + 127) / 128;   // 391 row blocks

    // L1: z1 = xbf @ [w1_rel | w1_root]
    gemm_v4<8, 4><<<rgrid * 4, 256, 0, stream>>>(xbf, pL1, nullptr, z1, 128, 0, 0, N);
    // h1 = relu( nbrsum(z1[:,:64]) + z1[:,64:] + b1 ) -> combo2[:,64:]
    agg_kernel_v2<8><<<(N * 16 + TB - 1) / TB, TB, 0, stream>>>(z1, 128, rp, csr,
                                                                z1 + 64, 128, b1, 1, combo2 + 64, 128, N);
    // agg2 = nbrsum(h1) -> combo2[:,:64]
    agg_kernel_v2<8><<<(N * 16 + TB - 1) / TB, TB, 0, stream>>>(combo2 + 64, 128, rp, csr,
                                                                nullptr, 0, nullptr, 0, combo2, 128, N);
    // L2: h2 = relu(combo2 @ [w2_rel; w2_root] + b2) -> combo3[:,128:]
    gemm_v4<8, 4><<<rgrid * 4, 256, 0, stream>>>(combo2, pL2, b2, combo3, 256, 128, 1, N);
    // agg3 = nbrsum(h2) -> combo3[:,:128]
    agg_kernel_v2<16><<<(N * 32 + TB - 1) / TB, TB, 0, stream>>>(combo3 + 128, 256, rp, csr,
                                                                 nullptr, 0, nullptr, 0, combo3, 256, N);
    // L3: h3 = relu(combo3 @ [w3_rel; w3_root] + b3)
    gemm_v4<16, 6><<<rgrid * 6, 256, 0, stream>>>(combo3, pL3, b3, h3, 192, 0, 1, N);

    // L4 folded with head
    st_kernel<<<(N * 64 + TB - 1) / TB, TB, 0, stream>>>(h3, wr, wt, sbuf, tbuf, N);
    aggpool_kernel<<<(N + TB - 1) / TB, TB, 0, stream>>>(sbuf, tbuf, rp, csr, batch, gsum, cnt, N);
    final_kernel<<<1, 64, 0, stream>>>(gsum, cnt, cbuf, head_b, out);
}

// Round 9
// 276.692 us; speedup vs baseline: 1.1022x; 1.0284x over previous
//
#include <hip/hip_runtime.h>

// GraphConv GNN forward, MI355X — Round 9.
// R8 post-mortem: gemm_v4 fetch-volume-bound — NC col-split re-reads A once per
// col-group, and consecutive blockIdx round-robins across XCDs so each re-read
// misses to HBM (L3 FETCH 78.7MB vs 25.6MB A). Fix: XCD-aware swizzle — all NC
// col-groups of a row-block share blockIdx%8 (same XCD) -> A served from L2.

#define NNODES 50000
#define NEDGES 800000
#define NGRAPH 64
#define NBUK 256                          // dst buckets
#define BSZ 196                           // nodes per bucket (196*256 >= 50000)
#define EPB (NEDGES / NBUK)               // 3125 edges per partition block
#define CVT_NB (NNODES * 128 / 4 / 256)   // 6250
#define PACK_NB (160 * 512 / 256)         // 320
#define RGRID ((NNODES + 127) / 128)      // 391 row blocks
#define RCHUNK ((RGRID + 7) / 8)          // 49 chunks of 8 row blocks

typedef __attribute__((ext_vector_type(8))) __bf16 bf16x8;
typedef __attribute__((ext_vector_type(16))) float f32x16;

__device__ __forceinline__ unsigned short f2bf(float f) {
    unsigned u = __float_as_uint(f);
    u += 0x7fff + ((u >> 16) & 1);   // RNE
    return (unsigned short)(u >> 16);
}
__device__ __forceinline__ float bf2f(unsigned b) {
    return __uint_as_float(b << 16);
}

// ---------------- CSR build: counting-sort partition ----------------

__global__ void hist_kernel(const int* __restrict__ dst, int* __restrict__ cnt) {
    __shared__ int h[NBUK];
    int tid = threadIdx.x, k = blockIdx.x;
    h[tid] = 0;
    __syncthreads();
    int end = (k + 1) * EPB;
    for (int i = k * EPB + tid; i < end; i += 256)
        atomicAdd(&h[dst[i] / BSZ], 1);
    __syncthreads();
    cnt[tid * NBUK + k] = h[tid];
}

__global__ void scan1_kernel(int* __restrict__ a, int* __restrict__ bsum, int n) {
    __shared__ int buf[256];
    int tid = threadIdx.x;
    int i = blockIdx.x * 256 + tid;
    int v = (i < n) ? a[i] : 0;
    buf[tid] = v;
    __syncthreads();
    #pragma unroll
    for (int off = 1; off < 256; off <<= 1) {
        int t = (tid >= off) ? buf[tid - off] : 0;
        __syncthreads();
        buf[tid] += t;
        __syncthreads();
    }
    if (i < n) a[i] = buf[tid] - v;            // local exclusive (in-place)
    if (tid == 255) bsum[blockIdx.x] = buf[255];
}

__global__ void scan2_kernel(int* __restrict__ bsum, int nb) {
    __shared__ int buf[256];
    int tid = threadIdx.x;
    int v = (tid < nb) ? bsum[tid] : 0;
    buf[tid] = v;
    __syncthreads();
    #pragma unroll
    for (int off = 1; off < 256; off <<= 1) {
        int t = (tid >= off) ? buf[tid - off] : 0;
        __syncthreads();
        buf[tid] += t;
        __syncthreads();
    }
    if (tid < nb) bsum[tid] = buf[tid] - v;
}

__global__ void scan3_kernel(int* __restrict__ a, const int* __restrict__ bsum, int n) {
    int i = blockIdx.x * 256 + threadIdx.x;
    if (i < n) a[i] += bsum[blockIdx.x];
}

__global__ void partition_kernel(const int* __restrict__ src, const int* __restrict__ dst,
                                 const int* __restrict__ cnt,
                                 unsigned long long* __restrict__ pedge) {
    __shared__ int lbase[NBUK];
    int tid = threadIdx.x, k = blockIdx.x;
    lbase[tid] = cnt[tid * NBUK + k];
    __syncthreads();
    int end = (k + 1) * EPB;
    for (int i = k * EPB + tid; i < end; i += 256) {
        int s = src[i], d = dst[i];
        int pos = atomicAdd(&lbase[d / BSZ], 1);
        pedge[pos] = (unsigned long long)(unsigned)s | ((unsigned long long)(unsigned)d << 32);
    }
}

__global__ void build_kernel(const unsigned long long* __restrict__ pedge,
                             const int* __restrict__ cnt,
                             int* __restrict__ rp, int* __restrict__ csr) {
    __shared__ int sdeg[256], sc[256], sbase[256], sfill[256];
    int tid = threadIdx.x, b = blockIdx.x;
    int node0 = b * BSZ;
    int ncnt = NNODES - node0;
    if (ncnt > BSZ) ncnt = BSZ;
    if (ncnt < 0) ncnt = 0;
    int seg0 = cnt[b * NBUK];
    int seg1 = (b + 1 < NBUK) ? cnt[(b + 1) * NBUK] : NEDGES;
    sdeg[tid] = 0;
    sfill[tid] = 0;
    __syncthreads();
    for (int i = seg0 + tid; i < seg1; i += 256)
        atomicAdd(&sdeg[(int)(pedge[i] >> 32) - node0], 1);
    __syncthreads();
    sc[tid] = sdeg[tid];
    __syncthreads();
    #pragma unroll
    for (int off = 1; off < 256; off <<= 1) {
        int t = (tid >= off) ? sc[tid - off] : 0;
        __syncthreads();
        sc[tid] += t;
        __syncthreads();
    }
    sbase[tid] = sc[tid] - sdeg[tid];          // exclusive within bucket
    if (tid < ncnt) rp[node0 + tid] = seg0 + sbase[tid];
    if (b == NBUK - 1 && tid == 0) rp[NNODES] = NEDGES;
    __syncthreads();
    for (int i = seg0 + tid; i < seg1; i += 256) {
        unsigned long long p = pedge[i];
        int d = (int)(p >> 32) - node0;
        int pos = atomicAdd(&sfill[d], 1);
        csr[seg0 + sbase[d] + pos] = (int)(p & 0xffffffffu);
    }
}

// ---------------- merged prep: cvt + weight pack + head fold ----------------

__device__ __forceinline__ void pack32(const float* __restrict__ W, unsigned short* __restrict__ dst,
                                       int KS_tot, int ks0, int dcols, int ct0,
                                       int tl, int ksl, int lane, int j) {
    int k = ksl * 16 + ((lane >> 5) << 3) + j;
    int col = tl * 32 + (lane & 31);
    dst[(((size_t)(ct0 + tl) * KS_tot + (ks0 + ksl)) * 64 + lane) * 8 + j] = f2bf(W[k * dcols + col]);
}

__global__ void prep_kernel(const float* __restrict__ x, unsigned short* __restrict__ xbf,
                            const float* __restrict__ w1_rel, const float* __restrict__ w1_root,
                            const float* __restrict__ w2_rel, const float* __restrict__ w2_root,
                            const float* __restrict__ w3_rel, const float* __restrict__ w3_root,
                            unsigned short* __restrict__ pL1, unsigned short* __restrict__ pL2,
                            unsigned short* __restrict__ pL3,
                            const float* __restrict__ w4_rel, const float* __restrict__ w4_root,
                            const float* __restrict__ b4, const float* __restrict__ head_w,
                            float* __restrict__ wr, float* __restrict__ wt,
                            float* __restrict__ cbuf) {
    int b = blockIdx.x;
    int tid = threadIdx.x;
    if (b < CVT_NB) {                       // fp32 -> bf16 of x
        int i = b * 256 + tid;
        float4 v = ((const float4*)x)[i];
        unsigned lo = (unsigned)f2bf(v.x) | ((unsigned)f2bf(v.y) << 16);
        unsigned hi = (unsigned)f2bf(v.z) | ((unsigned)f2bf(v.w) << 16);
        ((uint2*)xbf)[i] = make_uint2(lo, hi);
    } else if (b < CVT_NB + PACK_NB) {      // weight packing (32x32x16 B-frag order)
        int idx = (b - CVT_NB) * 256 + tid;
        int g = idx >> 9;
        int t = idx & 511;
        int lane = (t >> 3) & 63, j = t & 7;
        if (g < 16)       { int gl = g;       pack32(w1_rel,  pL1, 8,  0, 64,  0, gl / 8, gl % 8, lane, j); }
        else if (g < 32)  { int gl = g - 16;  pack32(w1_root, pL1, 8,  0, 64,  2, gl / 8, gl % 8, lane, j); }
        else if (g < 48)  { int gl = g - 32;  pack32(w2_rel,  pL2, 8,  0, 128, 0, gl / 4, gl % 4, lane, j); }
        else if (g < 64)  { int gl = g - 48;  pack32(w2_root, pL2, 8,  4, 128, 0, gl / 4, gl % 4, lane, j); }
        else if (g < 112) { int gl = g - 64;  pack32(w3_rel,  pL3, 16, 0, 192, 0, gl / 8, gl % 8, lane, j); }
        else              { int gl = g - 112; pack32(w3_root, pL3, 16, 8, 192, 0, gl / 8, gl % 8, lane, j); }
    } else {                                // head folding
        if (tid < 192) {
            float ar = 0.f, at = 0.f;
            for (int j = 0; j < 64; j++) {
                float hw = head_w[j];
                ar = fmaf(w4_rel[tid * 64 + j], hw, ar);
                at = fmaf(w4_root[tid * 64 + j], hw, at);
            }
            wr[tid] = ar;
            wt[tid] = at;
        } else if (tid == 192) {
            float c = 0.f;
            for (int j = 0; j < 64; j++) c = fmaf(b4[j], head_w[j], c);
            cbuf[0] = c;
        }
    }
}

// ---------------- MFMA GEMM v4 + XCD swizzle (32x32x16, all-register) --------
// One wave = 32 rows x 32 cols. blockIdx = chunk*(NC*8) + cg*8 + r,
// rowb = chunk*8 + r  ->  all NC col-groups of a row-block share blockIdx%8
// (same XCD under round-robin dispatch) so A is fetched from HBM once and
// L2-served for the rest. K in batches of 8 frags: 8 A + 8 B loads then 8 MFMAs.
// A frag: row = lane&31, k = (lane>>5)*8 + j. C/D: col = lane&31,
// row = (reg&3) + 8*(reg>>2) + 4*(lane>>5)   [verified m74/m101].

template<int KS, int NC>
__global__ __launch_bounds__(256, 4) void gemm_v4(
    const unsigned short* __restrict__ A, const unsigned short* __restrict__ W,
    const float* __restrict__ bias, unsigned short* __restrict__ OUT,
    int ldo, int ocol0, int relu, int N)
{
    const int K = KS * 16;
    int i = blockIdx.x;
    int chunk = i / (NC * 8);
    int rem = i - chunk * (NC * 8);
    int cg = rem >> 3;
    int rowb = chunk * 8 + (rem & 7);
    int tid = threadIdx.x;
    int wave = tid >> 6, lane = tid & 63;
    int l32 = lane & 31, half = lane >> 5;
    int rbase = rowb * 128 + wave * 32;
    if (rbase >= N) return;

    int arow = rbase + l32;
    if (arow >= N) arow = N - 1;   // clamp; garbage rows never stored
    const unsigned short* ap = A + (size_t)arow * K + half * 8;
    const unsigned short* wp = W + (size_t)cg * KS * 512 + lane * 8;

    f32x16 acc;
    #pragma unroll
    for (int r = 0; r < 16; r++) acc[r] = 0.f;

    #pragma unroll 1
    for (int kb = 0; kb < KS; kb += 8) {
        bf16x8 areg[8], breg[8];
        #pragma unroll
        for (int j = 0; j < 8; j++) {
            areg[j] = *(const bf16x8*)(ap + (kb + j) * 16);
            breg[j] = *(const bf16x8*)(wp + (size_t)(kb + j) * 512);
        }
        #pragma unroll
        for (int j = 0; j < 8; j++)
            acc = __builtin_amdgcn_mfma_f32_32x32x16_bf16(areg[j], breg[j], acc, 0, 0, 0);
    }

    int col = cg * 32 + l32;
    float bi = bias ? bias[col] : 0.f;
    #pragma unroll
    for (int reg = 0; reg < 16; reg++) {
        int row = rbase + (reg & 3) + 8 * (reg >> 2) + 4 * half;
        if (row < N) {
            float v = acc[reg] + bi;
            if (relu) v = fmaxf(v, 0.f);
            OUT[(size_t)row * ldo + ocol0 + col] = f2bf(v);
        }
    }
}

// ---------------- bf16 neighbor-sum via CSR gather ----------------

__device__ __forceinline__ void acc8(float* a, uint4 u) {
    a[0] += bf2f(u.x & 0xffffu); a[1] += bf2f(u.x >> 16);
    a[2] += bf2f(u.y & 0xffffu); a[3] += bf2f(u.y >> 16);
    a[4] += bf2f(u.z & 0xffffu); a[5] += bf2f(u.z >> 16);
    a[6] += bf2f(u.w & 0xffffu); a[7] += bf2f(u.w >> 16);
}

template<int LPF>
__global__ void agg_kernel_v2(const unsigned short* __restrict__ X, int ldx,
                              const int* __restrict__ rp, const int* __restrict__ csr,
                              const unsigned short* __restrict__ root, int ldr,
                              const float* __restrict__ bias, int relu,
                              unsigned short* __restrict__ OUT, int ldo, int N) {
    int t = blockIdx.x * blockDim.x + threadIdx.x;
    int node = t / (2 * LPF);
    int r = t % (2 * LPF);
    int sub = r / LPF;
    int sl = r % LPF;
    if (node >= N) return;
    float a[8] = {0.f, 0.f, 0.f, 0.f, 0.f, 0.f, 0.f, 0.f};
    int e0 = rp[node], e1 = rp[node + 1];
    const unsigned short* xb = X + 8 * sl;
    int e = e0 + sub;
    for (; e + 2 < e1; e += 4) {          // this sub: edges e, e+2
        int s0 = csr[e], s1 = csr[e + 2];
        uint4 u0 = *(const uint4*)(xb + (size_t)s0 * ldx);
        uint4 u1 = *(const uint4*)(xb + (size_t)s1 * ldx);
        acc8(a, u0);
        acc8(a, u1);
    }
    if (e < e1) {
        uint4 u = *(const uint4*)(xb + (size_t)csr[e] * ldx);
        acc8(a, u);
    }
    #pragma unroll
    for (int i = 0; i < 8; i++) a[i] += __shfl_xor(a[i], LPF, 64);
    if (sub == 0) {
        if (root) {
            uint4 u = *(const uint4*)(root + (size_t)node * ldr + 8 * sl);
            acc8(a, u);
        }
        if (bias) {
            float4 b0 = *(const float4*)(bias + 8 * sl);
            float4 b1 = *(const float4*)(bias + 8 * sl + 4);
            a[0] += b0.x; a[1] += b0.y; a[2] += b0.z; a[3] += b0.w;
            a[4] += b1.x; a[5] += b1.y; a[6] += b1.z; a[7] += b1.w;
        }
        if (relu) {
            #pragma unroll
            for (int i = 0; i < 8; i++) a[i] = fmaxf(a[i], 0.f);
        }
        uint4 o;
        o.x = (unsigned)f2bf(a[0]) | ((unsigned)f2bf(a[1]) << 16);
        o.y = (unsigned)f2bf(a[2]) | ((unsigned)f2bf(a[3]) << 16);
        o.z = (unsigned)f2bf(a[4]) | ((unsigned)f2bf(a[5]) << 16);
        o.w = (unsigned)f2bf(a[6]) | ((unsigned)f2bf(a[7]) << 16);
        *(uint4*)(OUT + (size_t)node * ldo + 8 * sl) = o;
    }
}

// ---------------- layer-4 tail ----------------

__global__ void st_kernel(const unsigned short* __restrict__ h3, const float* __restrict__ wr,
                          const float* __restrict__ wt, float* __restrict__ s,
                          float* __restrict__ t, int N) {
    int lane = threadIdx.x & 63;
    int node = (blockIdx.x * blockDim.x + threadIdx.x) >> 6;
    if (node >= N) return;
    float as = 0.f, at = 0.f;
    if (lane < 48) {
        uint2 u = *(const uint2*)(h3 + (size_t)node * 192 + 4 * lane);
        float x0 = bf2f(u.x & 0xffffu), x1 = bf2f(u.x >> 16);
        float x2 = bf2f(u.y & 0xffffu), x3 = bf2f(u.y >> 16);
        float4 r4 = *(const float4*)(wr + 4 * lane);
        float4 t4 = *(const float4*)(wt + 4 * lane);
        as = x0 * r4.x + x1 * r4.y + x2 * r4.z + x3 * r4.w;
        at = x0 * t4.x + x1 * t4.y + x2 * t4.z + x3 * t4.w;
    }
    #pragma unroll
    for (int off = 32; off > 0; off >>= 1) {
        as += __shfl_down(as, off, 64);
        at += __shfl_down(at, off, 64);
    }
    if (lane == 0) { s[node] = as; t[node] = at; }
}

__global__ void aggpool_kernel(const float* __restrict__ s, const float* __restrict__ t,
                               const int* __restrict__ rp, const int* __restrict__ csr,
                               const int* __restrict__ batch, float* __restrict__ gsum,
                               int* __restrict__ cnt, int N) {
    __shared__ float ls[NGRAPH];
    __shared__ int lc[NGRAPH];
    int tid = threadIdx.x;
    if (tid < NGRAPH) { ls[tid] = 0.f; lc[tid] = 0; }
    __syncthreads();
    int n = blockIdx.x * blockDim.x + tid;
    if (n < N) {
        float a = 0.f;
        int e = rp[n], e1 = rp[n + 1];
        for (; e + 3 < e1; e += 4) {
            int s0 = csr[e], s1 = csr[e + 1], s2 = csr[e + 2], s3 = csr[e + 3];
            a += s[s0] + s[s1] + s[s2] + s[s3];
        }
        for (; e < e1; e++) a += s[csr[e]];
        int g = batch[n];
        atomicAdd(&ls[g], a + t[n]);
        atomicAdd(&lc[g], 1);
    }
    __syncthreads();
    if (tid < NGRAPH && lc[tid] > 0) {
        atomicAdd(&gsum[tid], ls[tid]);
        atomicAdd(&cnt[tid], lc[tid]);
    }
}

__global__ void final_kernel(const float* __restrict__ gsum, const int* __restrict__ cnt,
                             const float* __restrict__ cbuf, const float* __restrict__ head_b,
                             float* __restrict__ out) {
    int g = threadIdx.x;
    if (g < NGRAPH) {
        float c = (float)(cnt[g] > 0 ? cnt[g] : 1);
        out[g] = gsum[g] / c + cbuf[0] + head_b[0];
    }
}

// ---------------- launch ----------------

extern "C" void kernel_launch(void* const* d_in, const int* in_sizes, int n_in,
                              void* d_out, int out_size, void* d_ws, size_t ws_size,
                              hipStream_t stream) {
    const float* x       = (const float*)d_in[0];
    const int*   edge    = (const int*)d_in[1];
    const int*   batch   = (const int*)d_in[2];
    const float* w1_rel  = (const float*)d_in[3];
    const float* w1_root = (const float*)d_in[4];
    const float* b1      = (const float*)d_in[5];
    const float* w2_rel  = (const float*)d_in[6];
    const float* w2_root = (const float*)d_in[7];
    const float* b2      = (const float*)d_in[8];
    const float* w3_rel  = (const float*)d_in[9];
    const float* w3_root = (const float*)d_in[10];
    const float* b3      = (const float*)d_in[11];
    const float* w4_rel  = (const float*)d_in[12];
    const float* w4_root = (const float*)d_in[13];
    const float* b4      = (const float*)d_in[14];
    const float* head_w  = (const float*)d_in[15];
    const float* head_b  = (const float*)d_in[16];
    float* out = (float*)d_out;

    const int N = NNODES, E = NEDGES;
    const int* src = edge;
    const int* dst = edge + E;

    char* ws = (char*)d_ws;
    size_t off = 0;
    auto alloc = [&](size_t bytes) -> char* {
        char* p = ws + off;
        off = (off + bytes + 255) & ~(size_t)255;
        return p;
    };
    // zeroed region first (single small memset): gsum, cnt
    float* gsum  = (float*)alloc(NGRAPH * 4);
    int*   cnt   = (int*)alloc(NGRAPH * 4);
    size_t zero_bytes = off;
    int*   bcnt  = (int*)alloc((size_t)NBUK * NBUK * 4);   // bucket x block counts
    int*   bsum  = (int*)alloc(256 * 4);
    int*   rp    = (int*)alloc((size_t)(N + 1) * 4);
    int*   csr   = (int*)alloc((size_t)E * 4);
    unsigned long long* pedge = (unsigned long long*)alloc((size_t)E * 8);
    unsigned short* xbf    = (unsigned short*)alloc((size_t)N * 128 * 2);
    unsigned short* z1     = (unsigned short*)alloc((size_t)N * 128 * 2);  // [x@w1_rel | x@w1_root]
    unsigned short* combo2 = (unsigned short*)alloc((size_t)N * 128 * 2);  // [agg2 | h1]
    unsigned short* combo3 = (unsigned short*)alloc((size_t)N * 256 * 2);  // [agg3 | h2]
    unsigned short* h3     = (unsigned short*)alloc((size_t)N * 192 * 2);
    unsigned short* pL1    = (unsigned short*)alloc(4 * 8 * 512 * 2);
    unsigned short* pL2    = (unsigned short*)alloc(4 * 8 * 512 * 2);
    unsigned short* pL3    = (unsigned short*)alloc(6 * 16 * 512 * 2);
    float* sbuf  = (float*)alloc((size_t)N * 4);
    float* tbuf  = (float*)alloc((size_t)N * 4);
    float* wr    = (float*)alloc(192 * 4);
    float* wt    = (float*)alloc(192 * 4);
    float* cbuf  = (float*)alloc(4);
    (void)ws_size;

    hipMemsetAsync(gsum, 0, zero_bytes, stream);

    const int TB = 256;

    // CSR build via counting-sort partition
    hist_kernel<<<NBUK, 256, 0, stream>>>(dst, bcnt);
    scan1_kernel<<<NBUK, 256, 0, stream>>>(bcnt, bsum, NBUK * NBUK);
    scan2_kernel<<<1, 256, 0, stream>>>(bsum, NBUK);
    scan3_kernel<<<NBUK, 256, 0, stream>>>(bcnt, bsum, NBUK * NBUK);
    partition_kernel<<<NBUK, 256, 0, stream>>>(src, dst, bcnt, pedge);
    build_kernel<<<NBUK, 256, 0, stream>>>(pedge, bcnt, rp, csr);

    // prep (cvt + pack + head fold in one launch)
    prep_kernel<<<CVT_NB + PACK_NB + 1, 256, 0, stream>>>(
        x, xbf, w1_rel, w1_root, w2_rel, w2_root, w3_rel, w3_root,
        pL1, pL2, pL3, w4_rel, w4_root, b4, head_w, wr, wt, cbuf);

    // L1: z1 = xbf @ [w1_rel | w1_root]
    gemm_v4<8, 4><<<RCHUNK * 8 * 4, 256, 0, stream>>>(xbf, pL1, nullptr, z1, 128, 0, 0, N);
    // h1 = relu( nbrsum(z1[:,:64]) + z1[:,64:] + b1 ) -> combo2[:,64:]
    agg_kernel_v2<8><<<(N * 16 + TB - 1) / TB, TB, 0, stream>>>(z1, 128, rp, csr,
                                                                z1 + 64, 128, b1, 1, combo2 + 64, 128, N);
    // agg2 = nbrsum(h1) -> combo2[:,:64]
    agg_kernel_v2<8><<<(N * 16 + TB - 1) / TB, TB, 0, stream>>>(combo2 + 64, 128, rp, csr,
                                                                nullptr, 0, nullptr, 0, combo2, 128, N);
    // L2: h2 = relu(combo2 @ [w2_rel; w2_root] + b2) -> combo3[:,128:]
    gemm_v4<8, 4><<<RCHUNK * 8 * 4, 256, 0, stream>>>(combo2, pL2, b2, combo3, 256, 128, 1, N);
    // agg3 = nbrsum(h2) -> combo3[:,:128]
    agg_kernel_v2<16><<<(N * 32 + TB - 1) / TB, TB, 0, stream>>>(combo3 + 128, 256, rp, csr,
                                                                 nullptr, 0, nullptr, 0, combo3, 256, N);
    // L3: h3 = relu(combo3 @ [w3_rel; w3_root] + b3)
    gemm_v4<16, 6><<<RCHUNK * 8 * 6, 256, 0, stream>>>(combo3, pL3, b3, h3, 192, 0, 1, N);

    // L4 folded with head
    st_kernel<<<(N * 64 + TB - 1) / TB, TB, 0, stream>>>(h3, wr, wt, sbuf, tbuf, N);
    aggpool_kernel<<<(N + TB - 1) / TB, TB, 0, stream>>>(sbuf, tbuf, rp, csr, batch, gsum, cnt, N);
    final_kernel<<<1, 64, 0, stream>>>(gsum, cnt, cbuf, head_b, out);
}